// Round 5
// baseline (165.736 us; speedup 1.0000x reference)
//
#include <hip/hip_runtime.h>

#define WIN    7
#define IMH    640
#define IMW    640
#define OHH    634            // IMH - WIN + 1
#define OWW    634
#define NB     64
#define NBANDS 24
#define BROWS  27             // 23*27 + 13 = 634 output rows
#define NTH    320            // 5 waves; 2 output cols per thread
#define NPART  (NB * NBANDS)  // 1536 partials

__device__ __forceinline__ float ssim_val(const float4& V, float C1, float C2,
                                          float inv_np, float covh) {
    float us  = V.x * inv_np, ud  = V.y * inv_np;
    float uss = V.z * inv_np, udd = V.w * inv_np;
    float p  = us * us, q = ud * ud;
    float pd = p - q,  ps = p + q;
    float A1 = fmaf(0.5f, pd, C1), B1 = fmaf(0.5f, ps, C1);
    float A2 = fmaf(covh, (uss - udd) - pd, C2);
    float B2 = fmaf(covh, (uss + udd) - ps, C2);
    return (A1 * A2) * __builtin_amdgcn_rcpf(B1 * B2);
}

__global__ __launch_bounds__(NTH, 4) void ssim_stream(
    const float* __restrict__ X, const float* __restrict__ Y,
    const float* __restrict__ dr, double* __restrict__ partial)
{
    __shared__ double sred[NTH / 64];

    const int tid  = threadIdx.x;
    const int band = blockIdx.x;
    const int b    = blockIdx.y;
    const int r0   = band * BROWS;

    // thread covers output cols 2t,2t+1; loads cols 2t..2t+7 (clamped at edge;
    // clamped threads' outputs are masked off via `active`).
    const int  cbase  = min(2 * tid, IMW - 8);
    const bool active = (tid < 317);

    const size_t ioff = (size_t)b * IMH * IMW + (size_t)r0 * IMW + cbase;
    const float* Xp = X + ioff;
    const float* Yp = Y + ioff;

    const float drv = dr[b];
    const float C1 = (0.01f * drv) * (0.01f * drv);
    const float C2 = (0.03f * drv) * (0.03f * drv);
    const float inv_np = 1.0f / 49.0f;
    const float covh   = (49.0f / 48.0f) * 0.5f;

    // 7-slot register ring of horizontal moment sums (Ss,Sd,Sss,Sdd) per col;
    // zero-init makes rows 0..5 a natural warm-up for the running V.
    float4 ring0[WIN], ring1[WIN];
    #pragma unroll
    for (int u = 0; u < WIN; ++u) {
        ring0[u] = make_float4(0.f, 0.f, 0.f, 0.f);
        ring1[u] = make_float4(0.f, 0.f, 0.f, 0.f);
    }
    float4 V0 = make_float4(0.f, 0.f, 0.f, 0.f);
    float4 V1 = make_float4(0.f, 0.f, 0.f, 0.f);

    // double-buffered row registers, parity-indexed (compile-time)
    float4 bx[2][2], by[2][2];
    double acc  = 0.0;
    float  esum = 0.f;

#define LOADROW(P, R) do {                                                    \
    const size_t o_ = (size_t)(R) * IMW;                                      \
    bx[P][0] = *(const float4*)(Xp + o_);                                     \
    bx[P][1] = *(const float4*)(Xp + o_ + 4);                                 \
    by[P][0] = *(const float4*)(Yp + o_);                                     \
    by[P][1] = *(const float4*)(Yp + o_ + 4);                                 \
} while (0)

#define COMPUTE(P, U, DOSSIM) do {                                            \
    const float4 xa = bx[P][0], xb = bx[P][1];                                \
    const float4 ya = by[P][0], yb = by[P][1];                                \
    const float4 sa = make_float4(xa.x+ya.x, xa.y+ya.y, xa.z+ya.z, xa.w+ya.w);\
    const float4 sb = make_float4(xb.x+yb.x, xb.y+yb.y, xb.z+yb.z, xb.w+yb.w);\
    const float4 da = make_float4(xa.x-ya.x, xa.y-ya.y, xa.z-ya.z, xa.w-ya.w);\
    const float4 db = make_float4(xb.x-yb.x, xb.y-yb.y, xb.z-yb.z, xb.w-yb.w);\
    const float hs0 = ((sa.x+sa.y)+(sa.z+sa.w)) + ((sb.x+sb.y)+sb.z);         \
    const float hs1 = (hs0 - sa.x) + sb.w;                                    \
    const float hd0 = ((da.x+da.y)+(da.z+da.w)) + ((db.x+db.y)+db.z);         \
    const float hd1 = (hd0 - da.x) + db.w;                                    \
    const float hss0 = fmaf(sa.x,sa.x, fmaf(sa.y,sa.y, fmaf(sa.z,sa.z,        \
                       fmaf(sa.w,sa.w, fmaf(sb.x,sb.x, fmaf(sb.y,sb.y,        \
                            sb.z*sb.z))))));                                  \
    const float hss1 = fmaf(sb.w,sb.w, hss0 - sa.x*sa.x);                     \
    const float hdd0 = fmaf(da.x,da.x, fmaf(da.y,da.y, fmaf(da.z,da.z,        \
                       fmaf(da.w,da.w, fmaf(db.x,db.x, fmaf(db.y,db.y,        \
                            db.z*db.z))))));                                  \
    const float hdd1 = fmaf(db.w,db.w, hdd0 - da.x*da.x);                     \
    V0.x += hs0  - ring0[U].x;  V0.y += hd0  - ring0[U].y;                    \
    V0.z += hss0 - ring0[U].z;  V0.w += hdd0 - ring0[U].w;                    \
    V1.x += hs1  - ring1[U].x;  V1.y += hd1  - ring1[U].y;                    \
    V1.z += hss1 - ring1[U].z;  V1.w += hdd1 - ring1[U].w;                    \
    ring0[U] = make_float4(hs0, hd0, hss0, hdd0);                             \
    ring1[U] = make_float4(hs1, hd1, hss1, hdd1);                             \
    if ((DOSSIM) && active) {                                                 \
        const float e0 = ssim_val(V0, C1, C2, inv_np, covh);                  \
        const float e1 = ssim_val(V1, C1, C2, inv_np, covh);                  \
        esum += e0 + e1;                                                      \
    }                                                                         \
} while (0)

    if (band < NBANDS - 1) {
        // ---- full band: 33 rows, software-pipelined (prefetch row r+1) ----
        LOADROW(0, 0);
        #pragma unroll 1
        for (int base = 0; base < 28; base += 14) {
            esum = 0.f;
            #pragma unroll
            for (int u = 0; u < 14; ++u) {
                LOADROW((u + 1) & 1, base + u + 1);   // rows 1..28
                COMPUTE(u & 1, (u % WIN), (base + u >= WIN - 1));
            }
            acc += (double)esum;
        }
        // epilogue rows 28..32 (row 28 already prefetched, parity 0)
        esum = 0.f;
        #pragma unroll
        for (int u = 0; u < 5; ++u) {
            if (u < 4) LOADROW((u + 1) & 1, 29 + u);
            COMPUTE(u & 1, u, 1);
        }
        acc += (double)esum;
    } else {
        // ---- last band (r0 = 621): 19 rows, guarded, unpipelined ----
        const int nrows = IMH - r0;   // 19
        for (int ch = 0; ch < 3; ++ch) {
            esum = 0.f;
            #pragma unroll
            for (int u = 0; u < WIN; ++u) {
                const int ur = ch * WIN + u;
                if (ur < nrows) {
                    LOADROW(0, ur);
                    COMPUTE(0, u, (ur >= WIN - 1));
                }
            }
            acc += (double)esum;
        }
    }

#undef LOADROW
#undef COMPUTE

    // ---- block reduction (5 waves) ----
    for (int off = 32; off > 0; off >>= 1)
        acc += __shfl_down(acc, off, 64);
    if ((tid & 63) == 0) sred[tid >> 6] = acc;
    __syncthreads();
    if (tid == 0) {
        double t = 0.0;
        #pragma unroll
        for (int k = 0; k < NTH / 64; ++k) t += sred[k];
        partial[(size_t)b * NBANDS + band] = t;
    }
}

__global__ __launch_bounds__(512) void ssim_reduce(
    const double* __restrict__ partial, int n2, float* __restrict__ out)
{
    const double2* p2 = (const double2*)partial;
    double acc = 0.0;
    for (int i = threadIdx.x; i < n2; i += 512) {
        double2 v = p2[i];
        acc += v.x + v.y;
    }
    for (int off = 32; off > 0; off >>= 1)
        acc += __shfl_down(acc, off, 64);
    __shared__ double sred[8];
    if ((threadIdx.x & 63) == 0) sred[threadIdx.x >> 6] = acc;
    __syncthreads();
    if (threadIdx.x == 0) {
        double t = 0.0;
        #pragma unroll
        for (int k = 0; k < 8; ++k) t += sred[k];
        double denom = (double)NB * (double)OHH * (double)OWW;
        out[0] = (float)(t / denom);
    }
}

extern "C" void kernel_launch(void* const* d_in, const int* in_sizes, int n_in,
                              void* d_out, int out_size, void* d_ws, size_t ws_size,
                              hipStream_t stream) {
    const float* X  = (const float*)d_in[0];
    const float* Y  = (const float*)d_in[1];
    const float* dr = (const float*)d_in[2];
    // d_in[3] is w = ones/49; constant-folded in-kernel.
    double* partial = (double*)d_ws;   // 1536 * 8 B = 12 KB scratch

    dim3 grid(NBANDS, NB);
    ssim_stream<<<grid, NTH, 0, stream>>>(X, Y, dr, partial);
    ssim_reduce<<<1, 512, 0, stream>>>(partial, NPART / 2, (float*)d_out);
}

// Round 6
// 63.775 us; speedup vs baseline: 2.5987x; 2.5987x over previous
//
#include <hip/hip_runtime.h>

#define WIN    7
#define IMH    640
#define IMW    640
#define OHH    634            // IMH - WIN + 1
#define OWW    634
#define NB     64
#define NBANDS 32
#define BROWS  20             // 31*20 + 14 = 634 output rows
#define NCT    5              // column tiles of 128 output cols
#define NPART  (NB * NBANDS * NCT)   // 10240 partials

__device__ __forceinline__ float ssim_val(const float4& V, float C1, float C2,
                                          float inv_np, float covh) {
    float us  = V.x * inv_np, ud  = V.y * inv_np;
    float uss = V.z * inv_np, udd = V.w * inv_np;
    float p  = us * us, q = ud * ud;
    float pd = p - q,  ps = p + q;
    float A1 = fmaf(0.5f, pd, C1), B1 = fmaf(0.5f, ps, C1);
    float A2 = fmaf(covh, (uss - udd) - pd, C2);
    float B2 = fmaf(covh, (uss + udd) - ps, C2);
    return (A1 * A2) * __builtin_amdgcn_rcpf(B1 * B2);
}

// One wave per block: no LDS, no barriers. Each lane owns 2 output cols.
__global__ __launch_bounds__(64, 4) void ssim_stream(
    const float* __restrict__ X, const float* __restrict__ Y,
    const float* __restrict__ dr, double* __restrict__ partial)
{
    const int lane = threadIdx.x;
    const int tile = blockIdx.x;          // 0..4 (128 output cols each)
    const int band = blockIdx.y;          // 0..31
    const int b    = blockIdx.z;          // image
    const int r0   = band * BROWS;
    const int nrows = min(BROWS + WIN - 1, IMH - r0);   // 26; last band 20

    const int  ocol   = tile * 128 + 2 * lane;          // first of 2 out cols
    const int  cbase  = min(ocol, IMW - 8);             // load cols cbase..cbase+7
    const bool active = (ocol <= OWW - 2);              // both cols valid (ocol<=632)

    const size_t ioff = (size_t)b * IMH * IMW + (size_t)r0 * IMW + cbase;
    const float* Xp = X + ioff;
    const float* Yp = Y + ioff;

    const float drv = dr[b];
    const float C1 = (0.01f * drv) * (0.01f * drv);
    const float C2 = (0.03f * drv) * (0.03f * drv);
    const float inv_np = 1.0f / 49.0f;
    const float covh   = (49.0f / 48.0f) * 0.5f;

    // 7-slot register ring of horizontal moment sums (Ss,Sd,Sss,Sdd) per col;
    // zero-init makes rows 0..5 a natural warm-up for the running V.
    float4 ring0[WIN], ring1[WIN];
    #pragma unroll
    for (int u = 0; u < WIN; ++u) {
        ring0[u] = make_float4(0.f, 0.f, 0.f, 0.f);
        ring1[u] = make_float4(0.f, 0.f, 0.f, 0.f);
    }
    float4 V0 = make_float4(0.f, 0.f, 0.f, 0.f);
    float4 V1 = make_float4(0.f, 0.f, 0.f, 0.f);

    double acc = 0.0;

    // rows unrolled by 7 so ring slot == u is compile-time (rule #20).
    for (int ch = 0; ch < 4; ++ch) {
        const int base = ch * WIN;
        float esum = 0.f;
        #pragma unroll
        for (int u = 0; u < WIN; ++u) {
            const int ur = base + u;
            if (ur < nrows) {                       // wave-uniform branch
                const size_t off = (size_t)ur * IMW;
                const float4 xa = *(const float4*)(Xp + off);
                const float4 xb = *(const float4*)(Xp + off + 4);
                const float4 ya = *(const float4*)(Yp + off);
                const float4 yb = *(const float4*)(Yp + off + 4);

                const float4 sa = make_float4(xa.x + ya.x, xa.y + ya.y,
                                              xa.z + ya.z, xa.w + ya.w);
                const float4 sb = make_float4(xb.x + yb.x, xb.y + yb.y,
                                              xb.z + yb.z, xb.w + yb.w);
                const float4 da = make_float4(xa.x - ya.x, xa.y - ya.y,
                                              xa.z - ya.z, xa.w - ya.w);
                const float4 db = make_float4(xb.x - yb.x, xb.y - yb.y,
                                              xb.z - yb.z, xb.w - yb.w);

                // horizontal 7-tap sums for the two output cols
                const float hs0 = ((sa.x + sa.y) + (sa.z + sa.w))
                                + ((sb.x + sb.y) + sb.z);
                const float hs1 = (hs0 - sa.x) + sb.w;
                const float hd0 = ((da.x + da.y) + (da.z + da.w))
                                + ((db.x + db.y) + db.z);
                const float hd1 = (hd0 - da.x) + db.w;
                const float hss0 = fmaf(sa.x, sa.x, fmaf(sa.y, sa.y,
                                   fmaf(sa.z, sa.z, fmaf(sa.w, sa.w,
                                   fmaf(sb.x, sb.x, fmaf(sb.y, sb.y,
                                        sb.z * sb.z))))));
                const float hss1 = fmaf(sb.w, sb.w, hss0 - sa.x * sa.x);
                const float hdd0 = fmaf(da.x, da.x, fmaf(da.y, da.y,
                                   fmaf(da.z, da.z, fmaf(da.w, da.w,
                                   fmaf(db.x, db.x, fmaf(db.y, db.y,
                                        db.z * db.z))))));
                const float hdd1 = fmaf(db.w, db.w, hdd0 - da.x * da.x);

                // running vertical sums: V += h_new - h[row-7] (ring slot u)
                V0.x += hs0  - ring0[u].x;  V0.y += hd0  - ring0[u].y;
                V0.z += hss0 - ring0[u].z;  V0.w += hdd0 - ring0[u].w;
                V1.x += hs1  - ring1[u].x;  V1.y += hd1  - ring1[u].y;
                V1.z += hss1 - ring1[u].z;  V1.w += hdd1 - ring1[u].w;
                ring0[u] = make_float4(hs0, hd0, hss0, hdd0);
                ring1[u] = make_float4(hs1, hd1, hss1, hdd1);

                if (active && ur >= WIN - 1) {
                    const float e0 = ssim_val(V0, C1, C2, inv_np, covh);
                    const float e1 = ssim_val(V1, C1, C2, inv_np, covh);
                    esum += e0 + e1;
                }
            }
        }
        acc += (double)esum;
    }

    // ---- wave reduction (single wave; no LDS, no barrier) ----
    for (int off = 32; off > 0; off >>= 1)
        acc += __shfl_down(acc, off, 64);
    if (lane == 0) {
        partial[((size_t)b * NBANDS + band) * NCT + tile] = acc;
    }
}

__global__ __launch_bounds__(512) void ssim_reduce(
    const double* __restrict__ partial, int n2, float* __restrict__ out)
{
    const double2* p2 = (const double2*)partial;
    double acc = 0.0;
    for (int i = threadIdx.x; i < n2; i += 512) {
        double2 v = p2[i];
        acc += v.x + v.y;
    }
    for (int off = 32; off > 0; off >>= 1)
        acc += __shfl_down(acc, off, 64);
    __shared__ double sred[8];
    if ((threadIdx.x & 63) == 0) sred[threadIdx.x >> 6] = acc;
    __syncthreads();
    if (threadIdx.x == 0) {
        double t = 0.0;
        #pragma unroll
        for (int k = 0; k < 8; ++k) t += sred[k];
        double denom = (double)NB * (double)OHH * (double)OWW;
        out[0] = (float)(t / denom);
    }
}

extern "C" void kernel_launch(void* const* d_in, const int* in_sizes, int n_in,
                              void* d_out, int out_size, void* d_ws, size_t ws_size,
                              hipStream_t stream) {
    const float* X  = (const float*)d_in[0];
    const float* Y  = (const float*)d_in[1];
    const float* dr = (const float*)d_in[2];
    // d_in[3] is w = ones/49; constant-folded in-kernel.
    double* partial = (double*)d_ws;   // 10240 * 8 B = 80 KB scratch

    dim3 grid(NCT, NBANDS, NB);
    ssim_stream<<<grid, 64, 0, stream>>>(X, Y, dr, partial);
    ssim_reduce<<<1, 512, 0, stream>>>(partial, NPART / 2, (float*)d_out);
}